// Round 17
// baseline (196.563 us; speedup 1.0000x reference)
//
#include <hip/hip_runtime.h>
#include <hip/hip_bf16.h>

// B=4, S=2048, QD=1024, NH=16, KVH=4, DH=64, WIN=256 (additive +1 mask, full softmax)

using short8 = __attribute__((ext_vector_type(8))) short;
using f32x2  = __attribute__((ext_vector_type(2))) float;
using f32x4  = __attribute__((ext_vector_type(4))) float;
using f32x16 = __attribute__((ext_vector_type(16))) float;
using uint2v = __attribute__((ext_vector_type(2))) unsigned int;

#define GLDS(g, l) __builtin_amdgcn_global_load_lds( \
    (const __attribute__((address_space(1))) void*)(g), \
    (__attribute__((address_space(3))) void*)(l), 16, 0, 0)

__device__ __forceinline__ unsigned short f2bf(float f) {
  union { float f; unsigned u; } v; v.f = f;
  unsigned r = v.u + 0x7fffu + ((v.u >> 16) & 1u);
  return (unsigned short)(r >> 16);
}

__device__ __forceinline__ unsigned cvtpk(float lo, float hi) {
  unsigned r;
  asm("v_cvt_pk_bf16_f32 %0, %1, %2" : "=v"(r) : "v"(lo), "v"(hi));
  return r;
}

__device__ __forceinline__ f32x2 mk2(float a, float b) { f32x2 r; r[0] = a; r[1] = b; return r; }

__device__ __forceinline__ f32x2 pk_add(f32x2 a, f32x2 b) {
  f32x2 r;
  asm("v_pk_add_f32 %0, %1, %2" : "=v"(r) : "v"(a), "v"(b));
  return r;
}

__device__ __forceinline__ f32x2 pk_fma(f32x2 a, f32x2 b, f32x2 c) {
  f32x2 r;
  asm("v_pk_fma_f32 %0, %1, %2, %3" : "=v"(r) : "v"(a), "v"(b), "v"(c));
  return r;
}

// fused coalesced weight transpose+convert: Wq/Wk/Wv -> WqkvT rows, Wo -> WoT.
__global__ __launch_bounds__(256) void wtr_kernel(
    const float* __restrict__ Wq, const float* __restrict__ Wk,
    const float* __restrict__ Wv, const float* __restrict__ Wo,
    unsigned short* __restrict__ WqkvT, unsigned short* __restrict__ WoT)
{
  __shared__ float tile[32][33];
  const int bx = blockIdx.x;
  const int by = blockIdx.y;
  const float* src; unsigned short* dst; int C, ct;
  if (by < 32)      { src = Wq; dst = WqkvT;               C = 1024; ct = by; }
  else if (by < 40) { src = Wk; dst = WqkvT + 1024 * 1024; C = 256;  ct = by - 32; }
  else if (by < 48) { src = Wv; dst = WqkvT + 1280 * 1024; C = 256;  ct = by - 40; }
  else              { src = Wo; dst = WoT;                 C = 1024; ct = by - 48; }
  const int tx = threadIdx.x & 31, ty = threadIdx.x >> 5;
  const int c0 = ct * 32, r0 = bx * 32;
#pragma unroll
  for (int i = 0; i < 4; ++i)
    tile[ty + i * 8][tx] = src[(size_t)(r0 + ty + i * 8) * C + c0 + tx];
  __syncthreads();
#pragma unroll
  for (int i = 0; i < 4; ++i) {
    int c = ty + i * 8;
    dst[(size_t)(c0 + c) * 1024 + r0 + tx] = f2bf(tile[tx][c]);
  }
}

// ---------------- fused QKV GEMM: X fp32 x WqkvT bf16 -> frag-major Q/K/V ----------------
__global__ __launch_bounds__(256) void qkv_gemm_kernel(
    const float* __restrict__ X, const unsigned short* __restrict__ Bt,
    unsigned short* __restrict__ Qo, unsigned short* __restrict__ Ko,
    unsigned short* __restrict__ Vto)
{
  __shared__ __align__(16) unsigned short As[2 * 4096];
  __shared__ __align__(16) unsigned short Bs[2 * 4096];
  const int id = blockIdx.x;                    // 768 blocks, 768 % 8 == 0
  const int swz = (id & 7) * 96 + (id >> 3);
  const int m0 = (swz & 63) * 128;
  const int n0 = (swz >> 6) * 128;
  const int t = threadIdx.x;
  const int w = t >> 6, l = t & 63;
  const int wr = w >> 1, wc = w & 1;

  f32x4 acc[4][4] = {};

  const size_t aoff = (size_t)(m0 + w * 16 + (l >> 2)) * 1024 + (size_t)((l & 3) * 8);
  const size_t boff = (size_t)(n0 + w * 16 + (l >> 2)) * 1024 + (size_t)((l & 3) * 8);
  const bool qk = (n0 < 1280);

  for (int kt = 0; kt < 1024; kt += 64) {
#pragma unroll
    for (int p = 0; p < 2; ++p) {
      GLDS(Bt + boff + kt + p * 32,             &Bs[p * 4096 + w * 512]);
      GLDS(Bt + boff + 64 * 1024 + kt + p * 32, &Bs[p * 4096 + (w + 4) * 512]);
      float4 fa0 = *reinterpret_cast<const float4*>(X + aoff + kt + p * 32);
      float4 fa1 = *reinterpret_cast<const float4*>(X + aoff + kt + p * 32 + 4);
      float4 fb0 = *reinterpret_cast<const float4*>(X + aoff + 64 * 1024 + kt + p * 32);
      float4 fb1 = *reinterpret_cast<const float4*>(X + aoff + 64 * 1024 + kt + p * 32 + 4);
      uint4 ua, ub;
      ua.x = cvtpk(fa0.x, fa0.y); ua.y = cvtpk(fa0.z, fa0.w);
      ua.z = cvtpk(fa1.x, fa1.y); ua.w = cvtpk(fa1.z, fa1.w);
      ub.x = cvtpk(fb0.x, fb0.y); ub.y = cvtpk(fb0.z, fb0.w);
      ub.z = cvtpk(fb1.x, fb1.y); ub.w = cvtpk(fb1.z, fb1.w);
      *reinterpret_cast<uint4*>(&As[p * 4096 + w * 512 + l * 8]) = ua;
      *reinterpret_cast<uint4*>(&As[p * 4096 + (w + 4) * 512 + l * 8]) = ub;
    }
    __syncthreads();

#pragma unroll
    for (int p = 0; p < 2; ++p) {
      short8 af[4], bfr[4];
#pragma unroll
      for (int mi = 0; mi < 4; ++mi) {
        int row = wr * 64 + mi * 16 + (l & 15);
        af[mi] = *reinterpret_cast<const short8*>(&As[p * 4096 + row * 32 + (l >> 4) * 8]);
      }
#pragma unroll
      for (int ni = 0; ni < 4; ++ni) {
        int row = wc * 64 + ni * 16 + (l & 15);
        bfr[ni] = *reinterpret_cast<const short8*>(&Bs[p * 4096 + row * 32 + (l >> 4) * 8]);
      }
      if (qk) {
#pragma unroll
        for (int mi = 0; mi < 4; ++mi)
#pragma unroll
          for (int ni = 0; ni < 4; ++ni)
            acc[mi][ni] = __builtin_amdgcn_mfma_f32_16x16x32_bf16(bfr[ni], af[mi], acc[mi][ni], 0, 0, 0);
      } else {
#pragma unroll
        for (int mi = 0; mi < 4; ++mi)
#pragma unroll
          for (int ni = 0; ni < 4; ++ni)
            acc[mi][ni] = __builtin_amdgcn_mfma_f32_16x16x32_bf16(af[mi], bfr[ni], acc[mi][ni], 0, 0, 0);
      }
    }
    __syncthreads();
  }

  const int lo = (l >> 4) * 4;

  if (qk) {
#pragma unroll
    for (int mi = 0; mi < 4; ++mi) {
      const int tok = m0 + wr * 64 + mi * 16 + (l & 15);
      const int bb = tok >> 11, ss = tok & 2047;
      const int T5 = ss >> 5, q5 = ss & 31;
#pragma unroll
      for (int ni = 0; ni < 4; ++ni) {
        const int ddb = n0 + wc * 64 + ni * 16;
        uint2 wv;
        wv.x = cvtpk(acc[mi][ni][0], acc[mi][ni][1]);
        wv.y = cvtpk(acc[mi][ni][2], acc[mi][ni][3]);
        size_t base; unsigned short* dstp;
        if (ddb < 1024) {
          int hh = ddb >> 6, kk = (ddb >> 4) & 3;
          base = ((((size_t)(bb * 16 + hh)) * 64 + T5) * 4 + kk) * 512; dstp = Qo;
        } else {
          int kvh = (ddb - 1024) >> 6, kk = (ddb >> 4) & 3;
          base = ((((size_t)(bb * 4 + kvh)) * 64 + T5) * 4 + kk) * 512; dstp = Ko;
        }
        *reinterpret_cast<uint2*>(dstp + base + (lo >> 3) * 256 + q5 * 8 + (lo & 7)) = wv;
      }
    }
  } else {
#pragma unroll
    for (int ni = 0; ni < 4; ++ni) {
      const int dd = n0 + wc * 64 + ni * 16 + (l & 15);
      const int kvh = (dd - 1280) >> 6, d6 = dd & 63;
#pragma unroll
      for (int mi = 0; mi < 4; ++mi) {
        const int tokb = m0 + wr * 64 + mi * 16 + lo;
        const int bb = tokb >> 11, ss = tokb & 2047;
        const int T5 = ss >> 5;
        const int f = (d6 >> 5) * 2 + (mi & 1);
        uint2 wv;
        wv.x = cvtpk(acc[mi][ni][0], acc[mi][ni][1]);
        wv.y = cvtpk(acc[mi][ni][2], acc[mi][ni][3]);
        size_t base = ((((size_t)(bb * 4 + kvh)) * 64 + T5) * 4 + f) * 512;
        *reinterpret_cast<uint2*>(Vto + base + ((lo >> 3) & 1) * 256 + (d6 & 31) * 8 + (lo & 7)) = wv;
      }
    }
  }
}

// ---------------- out-proj GEMM: AO bf16 x WoT bf16 -> out fp32 (BK=64 + XCD swizzle) ----------------
__global__ __launch_bounds__(256) void outproj_gemm_kernel(
    const unsigned short* __restrict__ A, const unsigned short* __restrict__ Bt,
    float* __restrict__ Co)
{
  __shared__ __align__(16) unsigned short As[2 * 4096];
  __shared__ __align__(16) unsigned short Bs[2 * 4096];
  const int id = blockIdx.x;                    // 512 blocks, 512 % 8 == 0
  const int swz = (id & 7) * 64 + (id >> 3);
  const int m0 = (swz & 63) * 128;
  const int n0 = (swz >> 6) * 128;
  const int t = threadIdx.x;
  const int w = t >> 6, l = t & 63;
  const int wr = w >> 1, wc = w & 1;

  f32x4 acc[4][4] = {};

  const size_t aoff = (size_t)(m0 + w * 16 + (l >> 2)) * 1024 + (size_t)((l & 3) * 8);
  const size_t boff = (size_t)(n0 + w * 16 + (l >> 2)) * 1024 + (size_t)((l & 3) * 8);

  for (int kt = 0; kt < 1024; kt += 64) {
#pragma unroll
    for (int p = 0; p < 2; ++p) {
      GLDS(A  + aoff + kt + p * 32,             &As[p * 4096 + w * 512]);
      GLDS(A  + aoff + 64 * 1024 + kt + p * 32, &As[p * 4096 + (w + 4) * 512]);
      GLDS(Bt + boff + kt + p * 32,             &Bs[p * 4096 + w * 512]);
      GLDS(Bt + boff + 64 * 1024 + kt + p * 32, &Bs[p * 4096 + (w + 4) * 512]);
    }
    __syncthreads();

#pragma unroll
    for (int p = 0; p < 2; ++p) {
      short8 af[4], bfr[4];
#pragma unroll
      for (int mi = 0; mi < 4; ++mi) {
        int row = wr * 64 + mi * 16 + (l & 15);
        af[mi] = *reinterpret_cast<const short8*>(&As[p * 4096 + row * 32 + (l >> 4) * 8]);
      }
#pragma unroll
      for (int ni = 0; ni < 4; ++ni) {
        int row = wc * 64 + ni * 16 + (l & 15);
        bfr[ni] = *reinterpret_cast<const short8*>(&Bs[p * 4096 + row * 32 + (l >> 4) * 8]);
      }
#pragma unroll
      for (int mi = 0; mi < 4; ++mi)
#pragma unroll
        for (int ni = 0; ni < 4; ++ni)
          acc[mi][ni] = __builtin_amdgcn_mfma_f32_16x16x32_bf16(af[mi], bfr[ni], acc[mi][ni], 0, 0, 0);
    }
    __syncthreads();
  }

#pragma unroll
  for (int mi = 0; mi < 4; ++mi)
#pragma unroll
    for (int ni = 0; ni < 4; ++ni)
#pragma unroll
      for (int r = 0; r < 4; ++r) {
        int m = m0 + wr * 64 + mi * 16 + (l >> 4) * 4 + r;
        int n = n0 + wc * 64 + ni * 16 + (l & 15);
        Co[((size_t)m << 10) + n] = acc[mi][ni][r];
      }
}

// ---------------- fused flash attention: static-max + per-wave KV phase-stagger ----------------
// Static-max softmax is order-independent -> wave w iterates tiles T = (i+16w)&63.
// Decorrelates the 4 resident waves' phases so one wave's MFMA cluster overlaps another's
// exp2/pack VALU work (pipes co-issue; setprio arbitrates in favor of MFMA).
__global__ __launch_bounds__(256, 4) void attn_kernel(
    const unsigned short* __restrict__ Qf, const unsigned short* __restrict__ Kf,
    const unsigned short* __restrict__ Vf, unsigned short* __restrict__ AO)
{
  const int t = threadIdx.x, w = t >> 6, l = t & 63;
  const int hi = l >> 5, ln = l & 31;

  const int orig = blockIdx.x;
  const int swz = (orig & 7) * 128 + (orig >> 3);
  const int hf = swz >> 4;
  const int qt = swz & 15;
  const int b = hf >> 4, h = hf & 15, kvh = h >> 2;
  const int q0 = qt * 128 + w * 32;
  const int qrow = q0 + ln;

  const unsigned short* Qp = Qf + (((size_t)hf * 64 + qt * 4 + w) * 4) * 512;
  const unsigned short* Kbase = Kf + ((size_t)(b * 4 + kvh) * 256) * 512 + l * 8;
  const unsigned short* Vbase = Vf + ((size_t)(b * 4 + kvh) * 256) * 512 + l * 8;

  short8 qf[4];
#pragma unroll
  for (int kk = 0; kk < 4; ++kk)
    qf[kk] = *reinterpret_cast<const short8*>(Qp + kk * 512 + l * 8);

  f32x16 oA = {}, oB = {};
  float lsum = 0.f;
  const float C1  = 0.125f * 1.44269504f;
  const float L2E = 1.44269504f;
  const float FM  = 12.0f;
  const f32x2 C1p = mk2(C1, C1);

  for (int i = 0; i < 64; ++i) {
    const int T = (i + w * 16) & 63;        // per-wave phase stagger (order-independent sum)
    const unsigned short* Kt = Kbase + (size_t)T * 2048;
    const unsigned short* Vt = Vbase + (size_t)T * 2048;
    short8 kf0 = *reinterpret_cast<const short8*>(Kt);
    short8 kf1 = *reinterpret_cast<const short8*>(Kt + 512);
    short8 kf2 = *reinterpret_cast<const short8*>(Kt + 1024);
    short8 kf3 = *reinterpret_cast<const short8*>(Kt + 1536);
    __builtin_amdgcn_s_setprio(1);
    f32x16 s = {};
    s = __builtin_amdgcn_mfma_f32_32x32x16_bf16(kf0, qf[0], s, 0, 0, 0);
    s = __builtin_amdgcn_mfma_f32_32x32x16_bf16(kf1, qf[1], s, 0, 0, 0);
    s = __builtin_amdgcn_mfma_f32_32x32x16_bf16(kf2, qf[2], s, 0, 0, 0);
    s = __builtin_amdgcn_mfma_f32_32x32x16_bf16(kf3, qf[3], s, 0, 0, 0);
    __builtin_amdgcn_s_setprio(0);
    short8 vf0 = *reinterpret_cast<const short8*>(Vt);
    short8 vf1 = *reinterpret_cast<const short8*>(Vt + 512);
    short8 vf2 = *reinterpret_cast<const short8*>(Vt + 1024);
    short8 vf3 = *reinterpret_cast<const short8*>(Vt + 1536);

    const int kv0 = T * 32;
    const int d = q0 - kv0;
    float p[16];
    if (d == 256 || d == -256) {            // mixed tile (2 of 64): scalar per-element mask
      const int qmb = qrow - kv0 - 4 * hi;
#pragma unroll
      for (int r = 0; r < 16; ++r) {
        const int kc = (r & 3) + 8 * (r >> 2);
        int df = qmb - kc; df = df < 0 ? -df : df;
        p[r] = __builtin_amdgcn_exp2f(
            __builtin_fmaf(s[r], C1, (df <= 256 ? L2E : 0.f) - FM));
      }
    } else {                                 // uniform tile: packed fma, scalar exp2
      const float cc = ((d <= 224 && d >= -224) ? L2E : 0.f) - FM;
      const f32x2 ccp = mk2(cc, cc);
#pragma unroll
      for (int j = 0; j < 8; ++j) {
        f32x2 sv = mk2(s[2 * j], s[2 * j + 1]);
        f32x2 tv = pk_fma(sv, C1p, ccp);
        p[2 * j]     = __builtin_amdgcn_exp2f(tv[0]);
        p[2 * j + 1] = __builtin_amdgcn_exp2f(tv[1]);
      }
    }

    // ---- row sum: packed-add tree (7 pk + 1 scalar) + permlane ----
    {
      f32x2 a0v = mk2(p[0], p[1]),  a1v = mk2(p[8],  p[9]);
      f32x2 b0v = mk2(p[2], p[3]),  b1v = mk2(p[10], p[11]);
      f32x2 c0v = mk2(p[4], p[5]),  c1v = mk2(p[12], p[13]);
      f32x2 d0v = mk2(p[6], p[7]),  d1v = mk2(p[14], p[15]);
      f32x2 q0v = pk_add(a0v, a1v);
      f32x2 q1v = pk_add(b0v, b1v);
      f32x2 q2v = pk_add(c0v, c1v);
      f32x2 q3v = pk_add(d0v, d1v);
      f32x2 r0 = pk_add(q0v, q2v);
      f32x2 r1 = pk_add(q1v, q3v);
      f32x2 u  = pk_add(r0, r1);
      float sum = u[0] + u[1];
      uint2v sw = __builtin_amdgcn_permlane32_swap(__float_as_uint(sum), __float_as_uint(sum), false, false);
      lsum += __uint_as_float(sw[0]) + __uint_as_float(sw[1]);
    }

    // ---- P^T -> bf16 B-frags (cvt_pk + permlane32_swap), PV ----
#pragma unroll
    for (int ks = 0; ks < 2; ++ks) {
      unsigned a0 = cvtpk(p[ks * 8 + 0], p[ks * 8 + 1]);
      unsigned a1 = cvtpk(p[ks * 8 + 2], p[ks * 8 + 3]);
      unsigned b0 = cvtpk(p[ks * 8 + 4], p[ks * 8 + 5]);
      unsigned b1 = cvtpk(p[ks * 8 + 6], p[ks * 8 + 7]);
      uint2v s0 = __builtin_amdgcn_permlane32_swap(a0, b0, false, false);
      uint2v s1 = __builtin_amdgcn_permlane32_swap(a1, b1, false, false);
      union { unsigned u[4]; short8 v; } pf;
      pf.u[0] = s0[0]; pf.u[1] = s1[0]; pf.u[2] = s0[1]; pf.u[3] = s1[1];
      __builtin_amdgcn_s_setprio(1);
      oA = __builtin_amdgcn_mfma_f32_32x32x16_bf16(ks ? vf1 : vf0, pf.v, oA, 0, 0, 0);
      oB = __builtin_amdgcn_mfma_f32_32x32x16_bf16(ks ? vf3 : vf2, pf.v, oB, 0, 0, 0);
      __builtin_amdgcn_s_setprio(0);
    }
  }

  const float inv = 1.f / lsum;
  unsigned short* Op = AO + ((size_t)(b * 2048 + qrow)) * 1024 + h * 64;
#pragma unroll
  for (int qd = 0; qd < 4; ++qd) {
    uint2 wv;
    wv.x = cvtpk(oA[4 * qd + 0] * inv, oA[4 * qd + 1] * inv);
    wv.y = cvtpk(oA[4 * qd + 2] * inv, oA[4 * qd + 3] * inv);
    *reinterpret_cast<uint2*>(Op + qd * 8 + hi * 4) = wv;
  }
#pragma unroll
  for (int qd = 0; qd < 4; ++qd) {
    uint2 wv;
    wv.x = cvtpk(oB[4 * qd + 0] * inv, oB[4 * qd + 1] * inv);
    wv.y = cvtpk(oB[4 * qd + 2] * inv, oB[4 * qd + 3] * inv);
    *reinterpret_cast<uint2*>(Op + 32 + qd * 8 + hi * 4) = wv;
  }
}

// ---------------- launcher ----------------
extern "C" void kernel_launch(void* const* d_in, const int* in_sizes, int n_in,
                              void* d_out, int out_size, void* d_ws, size_t ws_size,
                              hipStream_t stream)
{
  const float* X  = (const float*)d_in[0];
  const float* Wq = (const float*)d_in[1];
  const float* Wk = (const float*)d_in[2];
  const float* Wv = (const float*)d_in[3];
  const float* Wo = (const float*)d_in[4];
  float* out = (float*)d_out;
  char* ws = (char*)d_ws;

  unsigned short* WqkvT = (unsigned short*)(ws);                 // [1536][1024]       3 MB
  unsigned short* WoT   = (unsigned short*)(ws + 3145728);       // [1024][1024]       2 MB
  unsigned short* Q     = (unsigned short*)(ws + 5242880);       // Q frag-major      16 MB
  unsigned short* Kc    = (unsigned short*)(ws + 22020096);      // K frag-major       4 MB
  unsigned short* Vt    = (unsigned short*)(ws + 26214400);      // V^T frag-major     4 MB
  unsigned short* AO    = (unsigned short*)(ws + 30408704);      // [8192][1024]      16 MB

  wtr_kernel<<<dim3(32, 80), 256, 0, stream>>>(Wq, Wk, Wv, Wo, WqkvT, WoT);
  qkv_gemm_kernel<<<768, 256, 0, stream>>>(X, WqkvT, Q, Kc, Vt);
  attn_kernel<<<1024, 256, 0, stream>>>(Q, Kc, Vt, AO);
  outproj_gemm_kernel<<<512, 256, 0, stream>>>(AO, WoT, out);
}

// Round 18
// 191.176 us; speedup vs baseline: 1.0282x; 1.0282x over previous
//
#include <hip/hip_runtime.h>
#include <hip/hip_bf16.h>

// B=4, S=2048, QD=1024, NH=16, KVH=4, DH=64, WIN=256 (additive +1 mask, full softmax)

using short8 = __attribute__((ext_vector_type(8))) short;
using f32x2  = __attribute__((ext_vector_type(2))) float;
using f32x4  = __attribute__((ext_vector_type(4))) float;
using f32x16 = __attribute__((ext_vector_type(16))) float;
using uint2v = __attribute__((ext_vector_type(2))) unsigned int;

#define GLDS(g, l) __builtin_amdgcn_global_load_lds( \
    (const __attribute__((address_space(1))) void*)(g), \
    (__attribute__((address_space(3))) void*)(l), 16, 0, 0)

__device__ __forceinline__ unsigned short f2bf(float f) {
  union { float f; unsigned u; } v; v.f = f;
  unsigned r = v.u + 0x7fffu + ((v.u >> 16) & 1u);
  return (unsigned short)(r >> 16);
}

__device__ __forceinline__ unsigned cvtpk(float lo, float hi) {
  unsigned r;
  asm("v_cvt_pk_bf16_f32 %0, %1, %2" : "=v"(r) : "v"(lo), "v"(hi));
  return r;
}

__device__ __forceinline__ f32x2 mk2(float a, float b) { f32x2 r; r[0] = a; r[1] = b; return r; }

__device__ __forceinline__ f32x2 pk_add(f32x2 a, f32x2 b) {
  f32x2 r;
  asm("v_pk_add_f32 %0, %1, %2" : "=v"(r) : "v"(a), "v"(b));
  return r;
}

__device__ __forceinline__ f32x2 pk_fma(f32x2 a, f32x2 b, f32x2 c) {
  f32x2 r;
  asm("v_pk_fma_f32 %0, %1, %2, %3" : "=v"(r) : "v"(a), "v"(b), "v"(c));
  return r;
}

// fused coalesced weight transpose+convert: Wq/Wk/Wv -> WqkvT rows, Wo -> WoT.
__global__ __launch_bounds__(256) void wtr_kernel(
    const float* __restrict__ Wq, const float* __restrict__ Wk,
    const float* __restrict__ Wv, const float* __restrict__ Wo,
    unsigned short* __restrict__ WqkvT, unsigned short* __restrict__ WoT)
{
  __shared__ float tile[32][33];
  const int bx = blockIdx.x;
  const int by = blockIdx.y;
  const float* src; unsigned short* dst; int C, ct;
  if (by < 32)      { src = Wq; dst = WqkvT;               C = 1024; ct = by; }
  else if (by < 40) { src = Wk; dst = WqkvT + 1024 * 1024; C = 256;  ct = by - 32; }
  else if (by < 48) { src = Wv; dst = WqkvT + 1280 * 1024; C = 256;  ct = by - 40; }
  else              { src = Wo; dst = WoT;                 C = 1024; ct = by - 48; }
  const int tx = threadIdx.x & 31, ty = threadIdx.x >> 5;
  const int c0 = ct * 32, r0 = bx * 32;
#pragma unroll
  for (int i = 0; i < 4; ++i)
    tile[ty + i * 8][tx] = src[(size_t)(r0 + ty + i * 8) * C + c0 + tx];
  __syncthreads();
#pragma unroll
  for (int i = 0; i < 4; ++i) {
    int c = ty + i * 8;
    dst[(size_t)(c0 + c) * 1024 + r0 + tx] = f2bf(tile[tx][c]);
  }
}

// ---------------- fused QKV GEMM: X fp32 x WqkvT bf16 -> frag-major Q/K/V ----------------
// BK=64 (two 32-col panels per barrier pair) + bijective XCD swizzle (m-fastest within XCD
// so blocks on one XCD share the B-panel in its L2).
__global__ __launch_bounds__(256) void qkv_gemm_kernel(
    const float* __restrict__ X, const unsigned short* __restrict__ Bt,
    unsigned short* __restrict__ Qo, unsigned short* __restrict__ Ko,
    unsigned short* __restrict__ Vto)
{
  __shared__ __align__(16) unsigned short As[2 * 4096];
  __shared__ __align__(16) unsigned short Bs[2 * 4096];
  const int id = blockIdx.x;                    // 768 blocks, 768 % 8 == 0
  const int swz = (id & 7) * 96 + (id >> 3);
  const int m0 = (swz & 63) * 128;
  const int n0 = (swz >> 6) * 128;
  const int t = threadIdx.x;
  const int w = t >> 6, l = t & 63;
  const int wr = w >> 1, wc = w & 1;

  f32x4 acc[4][4] = {};

  const size_t aoff = (size_t)(m0 + w * 16 + (l >> 2)) * 1024 + (size_t)((l & 3) * 8);
  const size_t boff = (size_t)(n0 + w * 16 + (l >> 2)) * 1024 + (size_t)((l & 3) * 8);
  const bool qk = (n0 < 1280);

  for (int kt = 0; kt < 1024; kt += 64) {
#pragma unroll
    for (int p = 0; p < 2; ++p) {
      GLDS(Bt + boff + kt + p * 32,             &Bs[p * 4096 + w * 512]);
      GLDS(Bt + boff + 64 * 1024 + kt + p * 32, &Bs[p * 4096 + (w + 4) * 512]);
      float4 fa0 = *reinterpret_cast<const float4*>(X + aoff + kt + p * 32);
      float4 fa1 = *reinterpret_cast<const float4*>(X + aoff + kt + p * 32 + 4);
      float4 fb0 = *reinterpret_cast<const float4*>(X + aoff + 64 * 1024 + kt + p * 32);
      float4 fb1 = *reinterpret_cast<const float4*>(X + aoff + 64 * 1024 + kt + p * 32 + 4);
      uint4 ua, ub;
      ua.x = cvtpk(fa0.x, fa0.y); ua.y = cvtpk(fa0.z, fa0.w);
      ua.z = cvtpk(fa1.x, fa1.y); ua.w = cvtpk(fa1.z, fa1.w);
      ub.x = cvtpk(fb0.x, fb0.y); ub.y = cvtpk(fb0.z, fb0.w);
      ub.z = cvtpk(fb1.x, fb1.y); ub.w = cvtpk(fb1.z, fb1.w);
      *reinterpret_cast<uint4*>(&As[p * 4096 + w * 512 + l * 8]) = ua;
      *reinterpret_cast<uint4*>(&As[p * 4096 + (w + 4) * 512 + l * 8]) = ub;
    }
    __syncthreads();

#pragma unroll
    for (int p = 0; p < 2; ++p) {
      short8 af[4], bfr[4];
#pragma unroll
      for (int mi = 0; mi < 4; ++mi) {
        int row = wr * 64 + mi * 16 + (l & 15);
        af[mi] = *reinterpret_cast<const short8*>(&As[p * 4096 + row * 32 + (l >> 4) * 8]);
      }
#pragma unroll
      for (int ni = 0; ni < 4; ++ni) {
        int row = wc * 64 + ni * 16 + (l & 15);
        bfr[ni] = *reinterpret_cast<const short8*>(&Bs[p * 4096 + row * 32 + (l >> 4) * 8]);
      }
      if (qk) {
#pragma unroll
        for (int mi = 0; mi < 4; ++mi)
#pragma unroll
          for (int ni = 0; ni < 4; ++ni)
            acc[mi][ni] = __builtin_amdgcn_mfma_f32_16x16x32_bf16(bfr[ni], af[mi], acc[mi][ni], 0, 0, 0);
      } else {
#pragma unroll
        for (int mi = 0; mi < 4; ++mi)
#pragma unroll
          for (int ni = 0; ni < 4; ++ni)
            acc[mi][ni] = __builtin_amdgcn_mfma_f32_16x16x32_bf16(af[mi], bfr[ni], acc[mi][ni], 0, 0, 0);
      }
    }
    __syncthreads();
  }

  const int lo = (l >> 4) * 4;

  if (qk) {
#pragma unroll
    for (int mi = 0; mi < 4; ++mi) {
      const int tok = m0 + wr * 64 + mi * 16 + (l & 15);
      const int bb = tok >> 11, ss = tok & 2047;
      const int T5 = ss >> 5, q5 = ss & 31;
#pragma unroll
      for (int ni = 0; ni < 4; ++ni) {
        const int ddb = n0 + wc * 64 + ni * 16;
        uint2 wv;
        wv.x = cvtpk(acc[mi][ni][0], acc[mi][ni][1]);
        wv.y = cvtpk(acc[mi][ni][2], acc[mi][ni][3]);
        size_t base; unsigned short* dstp;
        if (ddb < 1024) {
          int hh = ddb >> 6, kk = (ddb >> 4) & 3;
          base = ((((size_t)(bb * 16 + hh)) * 64 + T5) * 4 + kk) * 512; dstp = Qo;
        } else {
          int kvh = (ddb - 1024) >> 6, kk = (ddb >> 4) & 3;
          base = ((((size_t)(bb * 4 + kvh)) * 64 + T5) * 4 + kk) * 512; dstp = Ko;
        }
        *reinterpret_cast<uint2*>(dstp + base + (lo >> 3) * 256 + q5 * 8 + (lo & 7)) = wv;
      }
    }
  } else {
#pragma unroll
    for (int ni = 0; ni < 4; ++ni) {
      const int dd = n0 + wc * 64 + ni * 16 + (l & 15);
      const int kvh = (dd - 1280) >> 6, d6 = dd & 63;
#pragma unroll
      for (int mi = 0; mi < 4; ++mi) {
        const int tokb = m0 + wr * 64 + mi * 16 + lo;
        const int bb = tokb >> 11, ss = tokb & 2047;
        const int T5 = ss >> 5;
        const int f = (d6 >> 5) * 2 + (mi & 1);
        uint2 wv;
        wv.x = cvtpk(acc[mi][ni][0], acc[mi][ni][1]);
        wv.y = cvtpk(acc[mi][ni][2], acc[mi][ni][3]);
        size_t base = ((((size_t)(bb * 4 + kvh)) * 64 + T5) * 4 + f) * 512;
        *reinterpret_cast<uint2*>(Vto + base + ((lo >> 3) & 1) * 256 + (d6 & 31) * 8 + (lo & 7)) = wv;
      }
    }
  }
}

// ---------------- out-proj GEMM: AO bf16 x WoT bf16 -> out fp32 (BK=64 + XCD swizzle) ----------------
__global__ __launch_bounds__(256) void outproj_gemm_kernel(
    const unsigned short* __restrict__ A, const unsigned short* __restrict__ Bt,
    float* __restrict__ Co)
{
  __shared__ __align__(16) unsigned short As[2 * 4096];
  __shared__ __align__(16) unsigned short Bs[2 * 4096];
  const int id = blockIdx.x;                    // 512 blocks, 512 % 8 == 0
  const int swz = (id & 7) * 64 + (id >> 3);
  const int m0 = (swz & 63) * 128;
  const int n0 = (swz >> 6) * 128;
  const int t = threadIdx.x;
  const int w = t >> 6, l = t & 63;
  const int wr = w >> 1, wc = w & 1;

  f32x4 acc[4][4] = {};

  const size_t aoff = (size_t)(m0 + w * 16 + (l >> 2)) * 1024 + (size_t)((l & 3) * 8);
  const size_t boff = (size_t)(n0 + w * 16 + (l >> 2)) * 1024 + (size_t)((l & 3) * 8);

  for (int kt = 0; kt < 1024; kt += 64) {
#pragma unroll
    for (int p = 0; p < 2; ++p) {
      GLDS(A  + aoff + kt + p * 32,             &As[p * 4096 + w * 512]);
      GLDS(A  + aoff + 64 * 1024 + kt + p * 32, &As[p * 4096 + (w + 4) * 512]);
      GLDS(Bt + boff + kt + p * 32,             &Bs[p * 4096 + w * 512]);
      GLDS(Bt + boff + 64 * 1024 + kt + p * 32, &Bs[p * 4096 + (w + 4) * 512]);
    }
    __syncthreads();

#pragma unroll
    for (int p = 0; p < 2; ++p) {
      short8 af[4], bfr[4];
#pragma unroll
      for (int mi = 0; mi < 4; ++mi) {
        int row = wr * 64 + mi * 16 + (l & 15);
        af[mi] = *reinterpret_cast<const short8*>(&As[p * 4096 + row * 32 + (l >> 4) * 8]);
      }
#pragma unroll
      for (int ni = 0; ni < 4; ++ni) {
        int row = wc * 64 + ni * 16 + (l & 15);
        bfr[ni] = *reinterpret_cast<const short8*>(&Bs[p * 4096 + row * 32 + (l >> 4) * 8]);
      }
#pragma unroll
      for (int mi = 0; mi < 4; ++mi)
#pragma unroll
        for (int ni = 0; ni < 4; ++ni)
          acc[mi][ni] = __builtin_amdgcn_mfma_f32_16x16x32_bf16(af[mi], bfr[ni], acc[mi][ni], 0, 0, 0);
    }
    __syncthreads();
  }

#pragma unroll
  for (int mi = 0; mi < 4; ++mi)
#pragma unroll
    for (int ni = 0; ni < 4; ++ni)
#pragma unroll
      for (int r = 0; r < 4; ++r) {
        int m = m0 + wr * 64 + mi * 16 + (l >> 4) * 4 + r;
        int n = n0 + wc * 64 + ni * 16 + (l & 15);
        Co[((size_t)m << 10) + n] = acc[mi][ni][r];
      }
}

// ---------------- fused flash attention (R16: static-max, frag-major, packed softmax, setprio) ----------------
__global__ __launch_bounds__(256, 4) void attn_kernel(
    const unsigned short* __restrict__ Qf, const unsigned short* __restrict__ Kf,
    const unsigned short* __restrict__ Vf, unsigned short* __restrict__ AO)
{
  const int t = threadIdx.x, w = t >> 6, l = t & 63;
  const int hi = l >> 5, ln = l & 31;

  const int orig = blockIdx.x;
  const int swz = (orig & 7) * 128 + (orig >> 3);
  const int hf = swz >> 4;
  const int qt = swz & 15;
  const int b = hf >> 4, h = hf & 15, kvh = h >> 2;
  const int q0 = qt * 128 + w * 32;
  const int qrow = q0 + ln;

  const unsigned short* Qp = Qf + (((size_t)hf * 64 + qt * 4 + w) * 4) * 512;
  const unsigned short* Kt = Kf + ((size_t)(b * 4 + kvh) * 256) * 512 + l * 8;
  const unsigned short* Vt = Vf + ((size_t)(b * 4 + kvh) * 256) * 512 + l * 8;

  short8 qf[4];
#pragma unroll
  for (int kk = 0; kk < 4; ++kk)
    qf[kk] = *reinterpret_cast<const short8*>(Qp + kk * 512 + l * 8);

  f32x16 oA = {}, oB = {};
  float lsum = 0.f;
  const float C1  = 0.125f * 1.44269504f;
  const float L2E = 1.44269504f;
  const float FM  = 12.0f;
  const f32x2 C1p = mk2(C1, C1);

  for (int T = 0; T < 64; ++T) {
    short8 kf0 = *reinterpret_cast<const short8*>(Kt);
    short8 kf1 = *reinterpret_cast<const short8*>(Kt + 512);
    short8 kf2 = *reinterpret_cast<const short8*>(Kt + 1024);
    short8 kf3 = *reinterpret_cast<const short8*>(Kt + 1536);
    __builtin_amdgcn_s_setprio(1);
    f32x16 s = {};
    s = __builtin_amdgcn_mfma_f32_32x32x16_bf16(kf0, qf[0], s, 0, 0, 0);
    s = __builtin_amdgcn_mfma_f32_32x32x16_bf16(kf1, qf[1], s, 0, 0, 0);
    s = __builtin_amdgcn_mfma_f32_32x32x16_bf16(kf2, qf[2], s, 0, 0, 0);
    s = __builtin_amdgcn_mfma_f32_32x32x16_bf16(kf3, qf[3], s, 0, 0, 0);
    __builtin_amdgcn_s_setprio(0);
    short8 vf0 = *reinterpret_cast<const short8*>(Vt);
    short8 vf1 = *reinterpret_cast<const short8*>(Vt + 512);
    short8 vf2 = *reinterpret_cast<const short8*>(Vt + 1024);
    short8 vf3 = *reinterpret_cast<const short8*>(Vt + 1536);
    Kt += 2048; Vt += 2048;

    const int kv0 = T * 32;
    const int d = q0 - kv0;
    float p[16];
    if (d == 256 || d == -256) {            // mixed tile (2 of 64): scalar per-element mask
      const int qmb = qrow - kv0 - 4 * hi;
#pragma unroll
      for (int r = 0; r < 16; ++r) {
        const int kc = (r & 3) + 8 * (r >> 2);
        int df = qmb - kc; df = df < 0 ? -df : df;
        p[r] = __builtin_amdgcn_exp2f(
            __builtin_fmaf(s[r], C1, (df <= 256 ? L2E : 0.f) - FM));
      }
    } else {                                 // uniform tile: packed fma, scalar exp2
      const float cc = ((d <= 224 && d >= -224) ? L2E : 0.f) - FM;
      const f32x2 ccp = mk2(cc, cc);
#pragma unroll
      for (int j = 0; j < 8; ++j) {
        f32x2 sv = mk2(s[2 * j], s[2 * j + 1]);
        f32x2 tv = pk_fma(sv, C1p, ccp);
        p[2 * j]     = __builtin_amdgcn_exp2f(tv[0]);
        p[2 * j + 1] = __builtin_amdgcn_exp2f(tv[1]);
      }
    }

    // ---- row sum: packed-add tree (7 pk + 1 scalar) + permlane ----
    {
      f32x2 a0v = mk2(p[0], p[1]),  a1v = mk2(p[8],  p[9]);
      f32x2 b0v = mk2(p[2], p[3]),  b1v = mk2(p[10], p[11]);
      f32x2 c0v = mk2(p[4], p[5]),  c1v = mk2(p[12], p[13]);
      f32x2 d0v = mk2(p[6], p[7]),  d1v = mk2(p[14], p[15]);
      f32x2 q0v = pk_add(a0v, a1v);
      f32x2 q1v = pk_add(b0v, b1v);
      f32x2 q2v = pk_add(c0v, c1v);
      f32x2 q3v = pk_add(d0v, d1v);
      f32x2 r0 = pk_add(q0v, q2v);
      f32x2 r1 = pk_add(q1v, q3v);
      f32x2 u  = pk_add(r0, r1);
      float sum = u[0] + u[1];
      uint2v sw = __builtin_amdgcn_permlane32_swap(__float_as_uint(sum), __float_as_uint(sum), false, false);
      lsum += __uint_as_float(sw[0]) + __uint_as_float(sw[1]);
    }

    // ---- P^T -> bf16 B-frags (cvt_pk + permlane32_swap), PV ----
#pragma unroll
    for (int ks = 0; ks < 2; ++ks) {
      unsigned a0 = cvtpk(p[ks * 8 + 0], p[ks * 8 + 1]);
      unsigned a1 = cvtpk(p[ks * 8 + 2], p[ks * 8 + 3]);
      unsigned b0 = cvtpk(p[ks * 8 + 4], p[ks * 8 + 5]);
      unsigned b1 = cvtpk(p[ks * 8 + 6], p[ks * 8 + 7]);
      uint2v s0 = __builtin_amdgcn_permlane32_swap(a0, b0, false, false);
      uint2v s1 = __builtin_amdgcn_permlane32_swap(a1, b1, false, false);
      union { unsigned u[4]; short8 v; } pf;
      pf.u[0] = s0[0]; pf.u[1] = s1[0]; pf.u[2] = s0[1]; pf.u[3] = s1[1];
      __builtin_amdgcn_s_setprio(1);
      oA = __builtin_amdgcn_mfma_f32_32x32x16_bf16(ks ? vf1 : vf0, pf.v, oA, 0, 0, 0);
      oB = __builtin_amdgcn_mfma_f32_32x32x16_bf16(ks ? vf3 : vf2, pf.v, oB, 0, 0, 0);
      __builtin_amdgcn_s_setprio(0);
    }
  }

  const float inv = 1.f / lsum;
  unsigned short* Op = AO + ((size_t)(b * 2048 + qrow)) * 1024 + h * 64;
#pragma unroll
  for (int qd = 0; qd < 4; ++qd) {
    uint2 wv;
    wv.x = cvtpk(oA[4 * qd + 0] * inv, oA[4 * qd + 1] * inv);
    wv.y = cvtpk(oA[4 * qd + 2] * inv, oA[4 * qd + 3] * inv);
    *reinterpret_cast<uint2*>(Op + qd * 8 + hi * 4) = wv;
  }
#pragma unroll
  for (int qd = 0; qd < 4; ++qd) {
    uint2 wv;
    wv.x = cvtpk(oB[4 * qd + 0] * inv, oB[4 * qd + 1] * inv);
    wv.y = cvtpk(oB[4 * qd + 2] * inv, oB[4 * qd + 3] * inv);
    *reinterpret_cast<uint2*>(Op + 32 + qd * 8 + hi * 4) = wv;
  }
}

// ---------------- launcher ----------------
extern "C" void kernel_launch(void* const* d_in, const int* in_sizes, int n_in,
                              void* d_out, int out_size, void* d_ws, size_t ws_size,
                              hipStream_t stream)
{
  const float* X  = (const float*)d_in[0];
  const float* Wq = (const float*)d_in[1];
  const float* Wk = (const float*)d_in[2];
  const float* Wv = (const float*)d_in[3];
  const float* Wo = (const float*)d_in[4];
  float* out = (float*)d_out;
  char* ws = (char*)d_ws;

  unsigned short* WqkvT = (unsigned short*)(ws);                 // [1536][1024]       3 MB
  unsigned short* WoT   = (unsigned short*)(ws + 3145728);       // [1024][1024]       2 MB
  unsigned short* Q     = (unsigned short*)(ws + 5242880);       // Q frag-major      16 MB
  unsigned short* Kc    = (unsigned short*)(ws + 22020096);      // K frag-major       4 MB
  unsigned short* Vt    = (unsigned short*)(ws + 26214400);      // V^T frag-major     4 MB
  unsigned short* AO    = (unsigned short*)(ws + 30408704);      // [8192][1024]      16 MB

  wtr_kernel<<<dim3(32, 80), 256, 0, stream>>>(Wq, Wk, Wv, Wo, WqkvT, WoT);
  qkv_gemm_kernel<<<768, 256, 0, stream>>>(X, WqkvT, Q, Kc, Vt);
  attn_kernel<<<1024, 256, 0, stream>>>(Q, Kc, Vt, AO);
  outproj_gemm_kernel<<<512, 256, 0, stream>>>(AO, WoT, out);
}